// Round 7
// baseline (732.667 us; speedup 1.0000x reference)
//
#include <hip/hip_runtime.h>
#include <hip/hip_fp16.h>

// B=2048 rows, T=2048 steps, H=32. Wave = ONE batch row; lane = (k, half).
// R6 structure (f16 fdot2 dots, permlane32_swap reduce/exchange, split
// activations, paired stores) with the register story fixed:
//  - waves_per_eu(2,2): occupancy is structurally 2 waves/SIMD (2048 waves /
//    1024 SIMDs), so let the RA use up to 256 VGPRs instead of minimizing.
//  - W asm-laundered once after load: rematerialization of the per-step
//    weight loads (R6: VGPR=52 < 32 W regs + rest) becomes impossible.
//  - x delivered via a double-buffered per-wave LDS line (1 ds_read_b32 per
//    step, zero VALU) instead of a 24-VGPR float4 prefetch pipeline.

#define Bsz 2048
#define Tsz 2048
#define Hsz 32

typedef _Float16 v2h __attribute__((ext_vector_type(2)));

__device__ __forceinline__ float fast_rcp(float x) { return __builtin_amdgcn_rcpf(x); }
__device__ __forceinline__ float fast_exp2(float x) { return __builtin_amdgcn_exp2f(x); }
__device__ __forceinline__ float fast_tanh(float x) {
    return __fmaf_rn(2.0f, fast_rcp(1.0f + fast_exp2(-2.885390082f * x)), -1.0f);
}

__device__ __forceinline__ float fdot2(v2h a, v2h b, float c) {
#if __has_builtin(__builtin_amdgcn_fdot2)
    return __builtin_amdgcn_fdot2(a, b, c, false);
#else
    return __fmaf_rn((float)a.x, (float)b.x, __fmaf_rn((float)a.y, (float)b.y, c));
#endif
}

// r0 = low-half-origin values (in all lanes), r1 = high-half-origin values.
__device__ __forceinline__ void plswap(float a, float b, float& r0, float& r1) {
#if __has_builtin(__builtin_amdgcn_permlane32_swap)
    auto r = __builtin_amdgcn_permlane32_swap(__float_as_uint(a), __float_as_uint(b),
                                              false, false);
    r0 = __uint_as_float(r[0]);
    r1 = __uint_as_float(r[1]);
#else
    const bool hi = (threadIdx.x & 32) != 0;
    r0 = hi ? __shfl_xor(b, 32) : a;
    r1 = hi ? b : __shfl_xor(a, 32);
#endif
}

__global__ __launch_bounds__(256)
__attribute__((amdgpu_waves_per_eu(2, 2)))
void lstm_fwd_kernel(
    const float* __restrict__ x,      // (B, T)
    const float* __restrict__ w_ih,   // (4H, 1)
    const float* __restrict__ w_hh,   // (4H, H)
    const float* __restrict__ b_ih,   // (4H,)
    const float* __restrict__ b_hh,   // (4H,)
    float* __restrict__ out)          // (B, T*H)
{
    __shared__ _Float16 hbuf[4][32];      // per-wave h line (64B)
    __shared__ float    xbuf[4][2][32];   // per-wave double-buffered x tiles

    const int lane = threadIdx.x & 63;
    const int k    = lane & 31;
    const int hf   = lane >> 5;                       // half: 0/1
    const int wv   = threadIdx.x >> 6;                // wave = row in block
    const int b    = blockIdx.x * 4 + wv;

    // ---- f16 weights: 4 gates x 8 v2h = 16-float k-slice each (32 VGPRs) ----
    v2h W[4][8];
#pragma unroll
    for (int g = 0; g < 4; ++g) {
        const float4* wr =
            reinterpret_cast<const float4*>(w_hh + (size_t)(g * 32 + k) * 32 + hf * 16);
#pragma unroll
        for (int q = 0; q < 4; ++q) {
            float4 v = wr[q];
            W[g][2 * q]     = (v2h){(_Float16)v.x, (_Float16)v.y};
            W[g][2 * q + 1] = (v2h){(_Float16)v.z, (_Float16)v.w};
        }
    }
    // launder: W becomes asm-defined -> remat of the global loads impossible;
    // with the 256-VGPR budget (waves_per_eu(2,2)) the RA keeps them resident.
#pragma unroll
    for (int g = 0; g < 4; ++g) {
        asm volatile("" : "+v"(W[g][0]), "+v"(W[g][1]), "+v"(W[g][2]), "+v"(W[g][3]),
                          "+v"(W[g][4]), "+v"(W[g][5]), "+v"(W[g][6]), "+v"(W[g][7]));
    }

    // per-half bias/x weights for the TWO gates this half activates
    const int gA = hf ? 2 : 0, gB = gA + 1;
    const float wiA = w_ih[gA * 32 + k], bsA = b_ih[gA * 32 + k] + b_hh[gA * 32 + k];
    const float wiB = w_ih[gB * 32 + k], bsB = b_ih[gB * 32 + k] + b_hh[gB * 32 + k];

    // unified activation: a1 = A1*rcp(1+exp2(B1*v)) + C1
    // hf0 -> sigmoid (i), hf1 -> tanh (g); second value always sigmoid
    const float B1 = hf ? -2.885390082f : -1.442695041f;
    const float A1 = hf ? 2.0f : 1.0f;
    const float C1 = hf ? -1.0f : 0.0f;

    float c = 0.0f, h = 0.0f, hprev = 0.0f;
    hbuf[wv][k] = (_Float16)0.0f;

    const float* xrow = x + (size_t)b * Tsz;
    float* op = out + (size_t)b * (size_t)(Tsz * Hsz) + hf * 32 + k;

    union Uq { uint4 q; v2h h2[4]; };

    auto run32 = [&](const float* xline) {
#pragma unroll
        for (int tt = 0; tt < 32; ++tt) {
            Uq u0 = *reinterpret_cast<const Uq*>(&hbuf[wv][hf * 16]);
            Uq u1 = *reinterpret_cast<const Uq*>(&hbuf[wv][hf * 16 + 8]);
            const float xt = xline[tt];

            float s0 = 0.0f, s1 = 0.0f, s2 = 0.0f, s3 = 0.0f;
#pragma unroll
            for (int j = 0; j < 4; ++j) {
                s0 = fdot2(W[0][j], u0.h2[j], s0);
                s1 = fdot2(W[1][j], u0.h2[j], s1);
                s2 = fdot2(W[2][j], u0.h2[j], s2);
                s3 = fdot2(W[3][j], u0.h2[j], s3);
            }
#pragma unroll
            for (int j = 0; j < 4; ++j) {
                s0 = fdot2(W[0][4 + j], u1.h2[j], s0);
                s1 = fdot2(W[1][4 + j], u1.h2[j], s1);
                s2 = fdot2(W[2][4 + j], u1.h2[j], s2);
                s3 = fdot2(W[3][4 + j], u1.h2[j], s3);
            }

            // cross-half reduce: hf0 lanes get p0/p1, hf1 lanes get p2/p3
            float r0, r1;
            plswap(s0, s2, r0, r1);
            const float v1 = (r0 + r1) + __fmaf_rn(wiA, xt, bsA);
            plswap(s1, s3, r0, r1);
            const float v2 = (r0 + r1) + __fmaf_rn(wiB, xt, bsB);

            // own-half activations (6 trans/step instead of 10)
            const float a1 = __fmaf_rn(A1, fast_rcp(1.0f + fast_exp2(B1 * v1)), C1);
            const float a2 = fast_rcp(1.0f + fast_exp2(-1.442695041f * v2));

            float i_, g_, f_, o_;
            plswap(a1, a1, i_, g_);   // i_ = sig(p0), g_ = tanh(p2), all lanes
            plswap(a2, a2, f_, o_);   // f_ = sig(p1), o_ = sig(p3), all lanes

            c = __fmaf_rn(f_, c, i_ * g_);
            h = o_ * fast_tanh(c);

            hbuf[wv][k] = (_Float16)h;

            if (tt & 1) {             // paired store: rows t-1 (hf0), t (hf1)
                *op = hf ? h : hprev;
                op += 64;
            } else {
                hprev = h;
            }
        }
    };

    // x pipeline: per-wave LDS tiles, one global load (1 VGPR) in flight.
    xbuf[wv][0][k] = xrow[k];                       // tile 0 (steps 0..31)
    float xv = xrow[32 + k];                        // tile 1 in flight

#pragma unroll 1
    for (int t0 = 0; t0 < Tsz; t0 += 64) {
        xbuf[wv][1][k] = xv;                        // tile (t0+32)
        int i1 = t0 + 64; if (i1 > Tsz - 32) i1 = Tsz - 32;   // clamp: dead value
        xv = xrow[i1 + k];                          // tile (t0+64) in flight
        run32(&xbuf[wv][0][0]);                     // steps t0 .. t0+31

        xbuf[wv][0][k] = xv;                        // tile (t0+64)
        int i2 = t0 + 96; if (i2 > Tsz - 32) i2 = Tsz - 32;
        xv = xrow[i2 + k];                          // tile (t0+96) in flight
        run32(&xbuf[wv][1][0]);                     // steps t0+32 .. t0+63
    }
}

extern "C" void kernel_launch(void* const* d_in, const int* in_sizes, int n_in,
                              void* d_out, int out_size, void* d_ws, size_t ws_size,
                              hipStream_t stream) {
    const float* x    = (const float*)d_in[0];
    const float* w_ih = (const float*)d_in[1];
    const float* w_hh = (const float*)d_in[2];
    const float* b_ih = (const float*)d_in[3];
    const float* b_hh = (const float*)d_in[4];
    float* out = (float*)d_out;

    dim3 grid(Bsz / 4);   // 512 blocks = 2 per CU -> 2 waves/SIMD
    dim3 block(256);      // 4 waves, each = one batch row (32 k x 2 halves)
    lstm_fwd_kernel<<<grid, block, 0, stream>>>(x, w_ih, w_hh, b_ih, b_hh, out);
}

// Round 8
// 606.226 us; speedup vs baseline: 1.2086x; 1.2086x over previous
//
#include <hip/hip_runtime.h>
#include <hip/hip_fp16.h>

// B=2048 rows, T=2048 steps, H=32. Wave = ONE batch row; lane = (k, gp).
// gp0 owns gates {i,f}, gp1 owns {g,o}, each with the FULL 32-wide h
// contraction (f16, v_dot2_f32_f16, fp32 accumulate) -> NO cross-lane
// reduce. Only cross-lane traffic: 2 permlane32_swap to exchange activated
// gate values (R6-verified semantics: r0 = low-half-origin value in all
// lanes, r1 = high-half-origin). h round-trip through a per-wave 64B f16
// LDS line (1 ds_write_b16 + 4 uniform ds_read_b128 per step). x via a
// 64-wide per-wave LDS tile (uniform ds_read_b32/step, refill per 64 steps).
// No asm laundering, no waves_per_eu (R7: 128-VGPR cap + spills = 700MB
// of scratch HBM traffic). 2048 waves = 2 waves/SIMD.

#define Bsz 2048
#define Tsz 2048
#define Hsz 32

typedef _Float16 v2h __attribute__((ext_vector_type(2)));

__device__ __forceinline__ float fast_rcp(float x) { return __builtin_amdgcn_rcpf(x); }
__device__ __forceinline__ float fast_exp2(float x) { return __builtin_amdgcn_exp2f(x); }

__device__ __forceinline__ float fdot2(uint a, uint b, float c) {
#if __has_builtin(__builtin_amdgcn_fdot2)
    return __builtin_amdgcn_fdot2(__builtin_bit_cast(v2h, a),
                                  __builtin_bit_cast(v2h, b), c, false);
#else
    v2h av = __builtin_bit_cast(v2h, a), bv = __builtin_bit_cast(v2h, b);
    return __fmaf_rn((float)av.x, (float)bv.x,
                     __fmaf_rn((float)av.y, (float)bv.y, c));
#endif
}

// r0 = low-half-origin values (in all lanes), r1 = high-half-origin values.
__device__ __forceinline__ void plswap(float a, float b, float& r0, float& r1) {
#if __has_builtin(__builtin_amdgcn_permlane32_swap)
    auto r = __builtin_amdgcn_permlane32_swap(__float_as_uint(a), __float_as_uint(b),
                                              false, false);
    r0 = __uint_as_float(r[0]);
    r1 = __uint_as_float(r[1]);
#else
    const bool hi = (threadIdx.x & 32) != 0;
    r0 = hi ? __shfl_xor(b, 32) : a;
    r1 = hi ? b : __shfl_xor(a, 32);
#endif
}

__global__ __launch_bounds__(256, 2) void lstm_fwd_kernel(
    const float* __restrict__ x,      // (B, T)
    const float* __restrict__ w_ih,   // (4H, 1)
    const float* __restrict__ w_hh,   // (4H, H)
    const float* __restrict__ b_ih,   // (4H,)
    const float* __restrict__ b_hh,   // (4H,)
    float* __restrict__ out)          // (B, T*H)
{
    __shared__ _Float16 hbuf[4][32];      // per-wave h line (64B)
    __shared__ float    xtile[4][2][64];  // per-wave double-buffered x

    const int lane = threadIdx.x & 63;
    const int k    = lane & 31;
    const int gp   = lane >> 5;           // 0: gates {i,f} ; 1: gates {g,o}
    const int wv   = threadIdx.x >> 6;
    const int b    = blockIdx.x * 4 + wv;

    // ---- f16 weights: rows jA = 64*gp + k (i or g), jB = jA + 32 (f or o);
    //      each row = 32 f16 = 16 dwords; total 32 VGPRs ----
    uint WA[16], WB[16];
    {
        const float* rA = w_hh + (size_t)(gp * 64 + k) * 32;
        const float* rB = rA + 32 * 32;
#pragma unroll
        for (int j = 0; j < 16; ++j) {
            WA[j] = __builtin_bit_cast(
                uint, (v2h){(_Float16)rA[2 * j], (_Float16)rA[2 * j + 1]});
            WB[j] = __builtin_bit_cast(
                uint, (v2h){(_Float16)rB[2 * j], (_Float16)rB[2 * j + 1]});
        }
    }
    const int jA = gp * 64 + k, jB = jA + 32;
    const float wiA = w_ih[jA], bsA = b_ih[jA] + b_hh[jA];
    const float wiB = w_ih[jB], bsB = b_ih[jB] + b_hh[jB];

    // unified activation: a1 = A1*rcp(1+exp2(B1*p)) + C1
    // gp0 -> sigmoid(i), gp1 -> tanh(g); second value always sigmoid
    const float B1 = gp ? -2.885390082f : -1.442695041f;
    const float A1 = gp ? 2.0f : 1.0f;
    const float C1 = gp ? -1.0f : 0.0f;

    float c = 0.0f, h = 0.0f, hprev = 0.0f;
    hbuf[wv][k] = (_Float16)0.0f;         // both halves same addr/value: benign

    const float* xrow = x + (size_t)b * Tsz;
    float* op = out + (size_t)b * (size_t)(Tsz * Hsz) + gp * 32 + k;
    const uint4* hl = reinterpret_cast<const uint4*>(&hbuf[wv][0]);

    // x pipeline: tile0 now, tile1 in flight
    xtile[wv][0][lane] = xrow[lane];
    float xv = xrow[64 + lane];

#pragma unroll 1
    for (int t0 = 0; t0 < Tsz; t0 += 64) {
        const int cur = (t0 >> 6) & 1;
        xtile[wv][cur ^ 1][lane] = xv;            // tile for steps t0+64..
        int pf = t0 + 128; if (pf >= Tsz) pf = Tsz - 64;  // clamped (dead)
        xv = xrow[pf + lane];
        const float* xl = &xtile[wv][cur][0];

#pragma unroll 1
        for (int tb = 0; tb < 64; tb += 8) {
#pragma unroll
            for (int u = 0; u < 8; ++u) {
                // previous h: 32 f16 as 4 uniform ds_read_b128
                uint4 q0 = hl[0], q1 = hl[1], q2 = hl[2], q3 = hl[3];
                const uint hh[16] = {q0.x, q0.y, q0.z, q0.w,
                                     q1.x, q1.y, q1.z, q1.w,
                                     q2.x, q2.y, q2.z, q2.w,
                                     q3.x, q3.y, q3.z, q3.w};
                const float xt = xl[tb + u];

                // 4 independent 8-deep dot chains (2 per gate)
                float sA0 = 0.f, sA1 = 0.f, sB0 = 0.f, sB1 = 0.f;
#pragma unroll
                for (int j = 0; j < 8; ++j) {
                    sA0 = fdot2(WA[j], hh[j], sA0);
                    sB0 = fdot2(WB[j], hh[j], sB0);
                }
#pragma unroll
                for (int j = 8; j < 16; ++j) {
                    sA1 = fdot2(WA[j], hh[j], sA1);
                    sB1 = fdot2(WB[j], hh[j], sB1);
                }
                const float pA = (sA0 + sA1) + __fmaf_rn(wiA, xt, bsA);
                const float pB = (sB0 + sB1) + __fmaf_rn(wiB, xt, bsB);

                // own-pair activations (4 trans) + tanh(c) (2 trans)
                const float a1 = __fmaf_rn(A1, fast_rcp(1.0f + fast_exp2(B1 * pA)), C1);
                const float a2 = fast_rcp(1.0f + fast_exp2(-1.442695041f * pB));

                float i_, g_, f_, o_;
                plswap(a1, a1, i_, g_);   // i_ = sig(i), g_ = tanh(g), all lanes
                plswap(a2, a2, f_, o_);   // f_ = sig(f), o_ = sig(o), all lanes

                c = __fmaf_rn(f_, c, i_ * g_);
                const float th =
                    __fmaf_rn(2.0f, fast_rcp(1.0f + fast_exp2(-2.885390082f * c)), -1.0f);
                h = o_ * th;

                hbuf[wv][k] = (_Float16)h;        // next step's input

                if (u & 1) {                      // paired store: t-1 (gp0), t (gp1)
                    *op = gp ? h : hprev;
                    op += 64;
                } else {
                    hprev = h;
                }
            }
        }
    }
}

extern "C" void kernel_launch(void* const* d_in, const int* in_sizes, int n_in,
                              void* d_out, int out_size, void* d_ws, size_t ws_size,
                              hipStream_t stream) {
    const float* x    = (const float*)d_in[0];
    const float* w_ih = (const float*)d_in[1];
    const float* w_hh = (const float*)d_in[2];
    const float* b_ih = (const float*)d_in[3];
    const float* b_hh = (const float*)d_in[4];
    float* out = (float*)d_out;

    dim3 grid(Bsz / 4);   // 512 blocks = 2 per CU -> 2 waves/SIMD
    dim3 block(256);      // 4 waves, each = one batch row (32 k x 2 gate-pairs)
    lstm_fwd_kernel<<<grid, block, 0, stream>>>(x, w_ih, w_hh, b_ih, b_hh, out);
}